// Round 10
// baseline (331.527 us; speedup 1.0000x reference)
//
#include <hip/hip_runtime.h>
#include <stdint.h>
#include <math.h>

#define T_TOK 512
#define DDIM  2048
#define IDIM  768
#define NEXP  16
#define TOPK  8
#define LDB   72    // LDS B row stride (bf16 units)

typedef __attribute__((ext_vector_type(8))) short bf16x8;
typedef __attribute__((ext_vector_type(4))) float f32x4;

// Barrier that does NOT drain outstanding global loads (vmcnt): only LDS ops.
__device__ __forceinline__ void lds_barrier() {
  asm volatile("s_waitcnt lgkmcnt(0)" ::: "memory");
  __builtin_amdgcn_s_barrier();
}

// ---------- fp8 e4m3fn RTNE quant-dequant (fp32-exact, result fits bf16) ----------
__device__ __forceinline__ float e4m3_rtne(float f) {
  uint32_t u = __float_as_uint(f);
  uint32_t sign = u & 0x80000000u;
  uint32_t a = u & 0x7FFFFFFFu;
  float fa = __uint_as_float(a);
  float out;
  if (fa >= 0.015625f) {            // normal: keep 3 mantissa bits, RTNE
    uint32_t lsb = (a >> 20) & 1u;
    a += 0x0007FFFFu + lsb;
    a &= 0xFFF00000u;
    out = __uint_as_float(a);
  } else {                          // subnormal: quantum 2^-9
    out = rintf(fa * 512.0f) * 0.001953125f;
  }
  return __uint_as_float(__float_as_uint(out) | sign);
}

// ---------- fused qdq (blocks 0..N-2) + routing (last block) ----------
__global__ __launch_bounds__(512) void qdq_route_kernel(
    const float* __restrict__ x, ushort* __restrict__ xq,
    const int* __restrict__ ids, const float* __restrict__ wts,
    int* __restrict__ counts, int* __restrict__ offsets,
    short* __restrict__ lists, float* __restrict__ combs)
{
  if ((int)blockIdx.x < (int)gridDim.x - 1) {
    int idx4 = blockIdx.x * 512 + threadIdx.x;
    float4 v = ((const float4*)x)[idx4];
    float a = fmaxf(fmaxf(fabsf(v.x), fabsf(v.y)), fmaxf(fabsf(v.z), fabsf(v.w)));
#pragma unroll
    for (int m = 4; m >= 1; m >>= 1)
      a = fmaxf(a, __shfl_xor(a, m, 8));
    a = fmaxf(a, 1e-4f);
    float scale = a / 448.0f;
    uint32_t b = __float_as_uint(scale);
    uint32_t ex = ((b >> 23) & 255u) + ((b & 0x7FFFFFu) ? 1u : 0u);
    ex = ex < 1u ? 1u : (ex > 254u ? 254u : ex);
    float rscale = __uint_as_float(ex << 23);
    float inv = 1.0f / rscale;
    uint32_t r0 = __float_as_uint(e4m3_rtne(v.x * inv) * rscale) >> 16;
    uint32_t r1 = __float_as_uint(e4m3_rtne(v.y * inv) * rscale) >> 16;
    uint32_t r2 = __float_as_uint(e4m3_rtne(v.z * inv) * rscale) >> 16;
    uint32_t r3 = __float_as_uint(e4m3_rtne(v.w * inv) * rscale) >> 16;
    ((uint2*)xq)[idx4] = make_uint2(r0 | (r1 << 16), r2 | (r3 << 16));
  } else {
    __shared__ int scnt[NEXP];
    int t = threadIdx.x;
    if (t < NEXP) scnt[t] = 0;
    __syncthreads();
    int  myid[TOPK];
    float myw[TOPK];
#pragma unroll
    for (int k = 0; k < TOPK; k++) { myid[k] = ids[t*TOPK+k]; myw[k] = wts[t*TOPK+k]; }
    for (int e = 0; e < NEXP; e++) {
      float s = 0.f; bool r = false;
#pragma unroll
      for (int k = 0; k < TOPK; k++) if (myid[k] == e) { s += myw[k]; r = true; }
      if (r) {
        int slot = atomicAdd(&scnt[e], 1);
        lists[(e<<9) + slot] = (short)t;
        combs[(e<<9) + slot] = s;
      }
    }
    __syncthreads();
    if (t == 0) {
      int acc = 0;
      for (int e = 0; e < NEXP; e++) {
        offsets[e] = acc;
        int c = scnt[e];
        counts[e] = c;
        acc += c;
      }
      offsets[NEXP] = acc;
    }
  }
}

// ---------- fp4 -> bf16 via v_perm LUT; S = (sf-1)<<1 ----------
__device__ __forceinline__ void deq4(int4 w, uint32_t S, ushort* dst) {
  uint32_t base = S << 6;
  uint32_t E01 = base << 16;                                   // e0=0 | e1=base
  uint32_t E23 = ((base + 192u) << 16) | (base + 128u);        // e2 | e3
  uint32_t E45 = ((base + 320u) << 16) | (base + 256u);        // e4 | e5
  uint32_t E67 = ((base + 448u) << 16) | (base + 384u);        // e6 | e7
  uint32_t lutLoA = __builtin_amdgcn_perm(E23, E01, 0x06040200u);
  uint32_t lutHiA = __builtin_amdgcn_perm(E23, E01, 0x07050301u);
  uint32_t lutLoB = __builtin_amdgcn_perm(E67, E45, 0x06040200u);
  uint32_t lutHiB = __builtin_amdgcn_perm(E67, E45, 0x07050301u);
  int wi[4] = {w.x, w.y, w.z, w.w};
  uint32_t od[4];
#pragma unroll
  for (int c = 0; c < 4; c += 2) {
    uint32_t a = (uint32_t)wi[c], b = (uint32_t)wi[c+1];
    uint32_t selm = ((a | (a << 4)) & 0x0707u) | ((((b | (b << 4)) & 0x0707u)) << 16);
    uint32_t sgn  = (((a << 4) | (a << 8)) & 0x8080u) | (((((b << 4) | (b << 8)) & 0x8080u)) << 16);
    uint32_t loB = __builtin_amdgcn_perm(lutLoB, lutLoA, selm);
    uint32_t hiB = __builtin_amdgcn_perm(lutHiB, lutHiA, selm) | sgn;
    od[c]   = __builtin_amdgcn_perm(hiB, loB, 0x05010400u);
    od[c+1] = __builtin_amdgcn_perm(hiB, loB, 0x07030602u);
  }
  *(uint4*)dst = make_uint4(od[0], od[1], od[2], od[3]);
}

// ---------- GEMM1: M=256 (4 waves x 64 rows), N=16 i-cols (gate+up -> 32 B-rows), BK=64 ----------
// B-frag reuse 4 (bfr[j] feeds 4 M-frags), deq4/thread, weights fetched ~once,
// 768 active blocks -> 3/CU -> 12 waves/CU.
__global__ __launch_bounds__(256,3) void gemm1_kernel(
    const ushort* __restrict__ xq, const int* __restrict__ w13,
    const int* __restrict__ w13s, const int* __restrict__ counts,
    const int* __restrict__ offsets, const short* __restrict__ lists,
    const float* __restrict__ combs, ushort* __restrict__ a_buf)
{
  const int e  = blockIdx.x;
  const int i0 = blockIdx.y << 4;
  const int m0 = blockIdx.z << 8;
  const int cnt = counts[e];
  if (m0 >= cnt) return;
  const int NIT = DDIM / 64;   // 32, even

  __shared__ __align__(16) ushort Bsh[2][32*LDB];
  __shared__ int   toks[256];
  __shared__ float cmbs[256];

  const int tid = threadIdx.x;
  {
    int m = m0 + tid; bool v = m < cnt;
    toks[tid] = v ? (int)lists[(e<<9)+m] : 0;
    cmbs[tid] = v ? combs[(e<<9)+m] : 0.f;
  }
  __syncthreads();

  const int wv = tid >> 6, l = tid & 63, l16 = l & 15, q = l >> 4;

  const ushort* arow[4];
#pragma unroll
  for (int i = 0; i < 4; i++)
    arow[i] = xq + (size_t)toks[wv*64 + i*16 + l16]*DDIM + q*8;

  const int rb = tid >> 3, hq = tid & 7;               // 32 B-rows, 8 thr/row, 4 ints each
  const int feat = (rb < 16) ? (i0 + rb) : (IDIM + i0 + (rb - 16));
  const int* wrow = w13 + ((size_t)e*(2*IDIM) + feat)*(DDIM/2) + hq*4;
  const int* srow = w13s + ((size_t)e*(2*IDIM) + feat)*(DDIM/32) + (hq >> 2);
  const int bdst = rb*LDB + hq*8;

  f32x4 acc[4][2];
#pragma unroll
  for (int i = 0; i < 4; i++)
#pragma unroll
    for (int j = 0; j < 2; j++) acc[i][j] = (f32x4){0.f,0.f,0.f,0.f};

  bf16x8 aA[4][2], aB[4][2];
  int4 wA, wB; uint32_t SA, SB;

  // ---- prologue ----
  {
    int4 t0 = *(const int4*)(wrow);
    uint32_t S = (((uint32_t)srow[0]) - 1u) << 1;
    deq4(t0, S, &Bsh[0][bdst]);
  }
#pragma unroll
  for (int i = 0; i < 4; i++)
#pragma unroll
    for (int s = 0; s < 2; s++)
      aA[i][s] = *(const bf16x8*)(arow[i] + s*32);          // a(0)
  wA = *(const int4*)(wrow + 32);
  SA = (((uint32_t)srow[2]) - 1u) << 1;                     // w(1)
#pragma unroll
  for (int i = 0; i < 4; i++)
#pragma unroll
    for (int s = 0; s < 2; s++)
      aB[i][s] = *(const bf16x8*)(arow[i] + 64 + s*32);     // a(1)
  lds_barrier();

  for (int t = 0; t < NIT; t += 2) {
    // ---- even sub-iter: MFMA(LDS0, aA); dequant wA=w(t+1)->LDS1; load w(t+2)->wB, a(t+2)->aA
    int t2 = t + 2 < NIT ? t + 2 : NIT - 1;
    wB = *(const int4*)(wrow + t2*32);
    SB = (((uint32_t)srow[t2*2]) - 1u) << 1;
#pragma unroll
    for (int s = 0; s < 2; s++) {
      bf16x8 bfr[2];
#pragma unroll
      for (int j = 0; j < 2; j++)
        bfr[j] = *(const bf16x8*)&Bsh[0][(j*16 + l16)*LDB + s*32 + q*8];
#pragma unroll
      for (int i = 0; i < 4; i++)
#pragma unroll
        for (int j = 0; j < 2; j++)
          acc[i][j] = __builtin_amdgcn_mfma_f32_16x16x32_bf16(aA[i][s], bfr[j], acc[i][j], 0, 0, 0);
    }
    deq4(wA, SA, &Bsh[1][bdst]);
#pragma unroll
    for (int i = 0; i < 4; i++)
#pragma unroll
      for (int s = 0; s < 2; s++)
        aA[i][s] = *(const bf16x8*)(arow[i] + t2*64 + s*32);
    lds_barrier();

    // ---- odd sub-iter: MFMA(LDS1, aB); dequant wB=w(t+2)->LDS0; load w(t+3)->wA, a(t+3)->aB
    int t3 = t + 3 < NIT ? t + 3 : NIT - 1;
    wA = *(const int4*)(wrow + t3*32);
    SA = (((uint32_t)srow[t3*2]) - 1u) << 1;
#pragma unroll
    for (int s = 0; s < 2; s++) {
      bf16x8 bfr[2];
#pragma unroll
      for (int j = 0; j < 2; j++)
        bfr[j] = *(const bf16x8*)&Bsh[1][(j*16 + l16)*LDB + s*32 + q*8];
#pragma unroll
      for (int i = 0; i < 4; i++)
#pragma unroll
        for (int j = 0; j < 2; j++)
          acc[i][j] = __builtin_amdgcn_mfma_f32_16x16x32_bf16(aB[i][s], bfr[j], acc[i][j], 0, 0, 0);
    }
    deq4(wB, SB, &Bsh[0][bdst]);
#pragma unroll
    for (int i = 0; i < 4; i++)
#pragma unroll
      for (int s = 0; s < 2; s++)
        aB[i][s] = *(const bf16x8*)(arow[i] + t3*64 + s*32);
    lds_barrier();
  }

  const int obase = offsets[e];
#pragma unroll
  for (int i = 0; i < 4; i++) {
#pragma unroll
    for (int r = 0; r < 4; r++) {
      int mrow = wv*64 + i*16 + q*4 + r;   // C/D: row=(lane>>4)*4+reg, col=lane&15
      int gm = m0 + mrow;
      if (gm < cnt) {
        float c = cmbs[mrow];
        float g = acc[i][0][r], u = acc[i][1][r];
        float val = (g / (1.f + expf(-g))) * u * c;   // comb folded (linear downstream)
        uint32_t bb = __float_as_uint(val);
        bb += 0x7FFFu + ((bb >> 16) & 1u);            // RTNE to bf16
        a_buf[(size_t)(obase + gm)*IDIM + i0 + l16] = (ushort)(bb >> 16);
      }
    }
  }
}

// ---------- GEMM2: M=256 (4 waves x 64), N=32 d-cols, BK=64, fused combine ----------
__global__ __launch_bounds__(256,3) void gemm2_kernel(
    const ushort* __restrict__ a_buf, const int* __restrict__ w2,
    const int* __restrict__ w2s, const int* __restrict__ counts,
    const int* __restrict__ offsets, const short* __restrict__ lists,
    float* __restrict__ out)
{
  const int e  = blockIdx.x;
  const int n0 = blockIdx.y << 5;
  const int m0 = blockIdx.z << 8;
  const int cnt = counts[e];
  if (m0 >= cnt) return;
  const int NIT = IDIM / 64;   // 12, even

  __shared__ __align__(16) ushort Bsh[2][32*LDB];

  const int tid = threadIdx.x;
  const int wv = tid >> 6, l = tid & 63, l16 = l & 15, q = l >> 4;
  const int obase = offsets[e];

  const ushort* arow[4];
#pragma unroll
  for (int i = 0; i < 4; i++) {
    int gm = m0 + wv*64 + i*16 + l16;
    int rowc = (gm < cnt) ? gm : 0;
    arow[i] = a_buf + (size_t)(obase + rowc)*IDIM + q*8;
  }

  const int rb = tid >> 3, hq = tid & 7;               // 32 B-rows, 8 thr/row, 4 ints each
  const int* wrow = w2 + ((size_t)e*DDIM + n0 + rb)*(IDIM/2) + hq*4;
  const int* srow = w2s + ((size_t)e*DDIM + n0 + rb)*(IDIM/32) + (hq >> 2);
  const int bdst = rb*LDB + hq*8;

  f32x4 acc[4][2];
#pragma unroll
  for (int i = 0; i < 4; i++)
#pragma unroll
    for (int j = 0; j < 2; j++) acc[i][j] = (f32x4){0.f,0.f,0.f,0.f};

  bf16x8 aA[4][2], aB[4][2];
  int4 wA, wB; uint32_t SA, SB;

  {
    int4 t0 = *(const int4*)(wrow);
    uint32_t S = (((uint32_t)srow[0]) - 1u) << 1;
    deq4(t0, S, &Bsh[0][bdst]);
  }
#pragma unroll
  for (int i = 0; i < 4; i++)
#pragma unroll
    for (int s = 0; s < 2; s++)
      aA[i][s] = *(const bf16x8*)(arow[i] + s*32);
  wA = *(const int4*)(wrow + 32);
  SA = (((uint32_t)srow[2]) - 1u) << 1;
#pragma unroll
  for (int i = 0; i < 4; i++)
#pragma unroll
    for (int s = 0; s < 2; s++)
      aB[i][s] = *(const bf16x8*)(arow[i] + 64 + s*32);
  lds_barrier();

  for (int t = 0; t < NIT; t += 2) {
    int t2 = t + 2 < NIT ? t + 2 : NIT - 1;
    wB = *(const int4*)(wrow + t2*32);
    SB = (((uint32_t)srow[t2*2]) - 1u) << 1;
#pragma unroll
    for (int s = 0; s < 2; s++) {
      bf16x8 bfr[2];
#pragma unroll
      for (int j = 0; j < 2; j++)
        bfr[j] = *(const bf16x8*)&Bsh[0][(j*16 + l16)*LDB + s*32 + q*8];
#pragma unroll
      for (int i = 0; i < 4; i++)
#pragma unroll
        for (int j = 0; j < 2; j++)
          acc[i][j] = __builtin_amdgcn_mfma_f32_16x16x32_bf16(aA[i][s], bfr[j], acc[i][j], 0, 0, 0);
    }
    deq4(wA, SA, &Bsh[1][bdst]);
#pragma unroll
    for (int i = 0; i < 4; i++)
#pragma unroll
      for (int s = 0; s < 2; s++)
        aA[i][s] = *(const bf16x8*)(arow[i] + t2*64 + s*32);
    lds_barrier();

    int t3 = t + 3 < NIT ? t + 3 : NIT - 1;
    wA = *(const int4*)(wrow + t3*32);
    SA = (((uint32_t)srow[t3*2]) - 1u) << 1;
#pragma unroll
    for (int s = 0; s < 2; s++) {
      bf16x8 bfr[2];
#pragma unroll
      for (int j = 0; j < 2; j++)
        bfr[j] = *(const bf16x8*)&Bsh[1][(j*16 + l16)*LDB + s*32 + q*8];
#pragma unroll
      for (int i = 0; i < 4; i++)
#pragma unroll
        for (int j = 0; j < 2; j++)
          acc[i][j] = __builtin_amdgcn_mfma_f32_16x16x32_bf16(aB[i][s], bfr[j], acc[i][j], 0, 0, 0);
    }
    deq4(wB, SB, &Bsh[0][bdst]);
#pragma unroll
    for (int i = 0; i < 4; i++)
#pragma unroll
      for (int s = 0; s < 2; s++)
        aB[i][s] = *(const bf16x8*)(arow[i] + t3*64 + s*32);
    lds_barrier();
  }

#pragma unroll
  for (int i = 0; i < 4; i++) {
#pragma unroll
    for (int r = 0; r < 4; r++) {
      int mrow = wv*64 + i*16 + q*4 + r;
      int gm = m0 + mrow;
      if (gm < cnt) {
        int tok = (int)lists[(e<<9) + gm];
        float* dst = out + (size_t)tok*DDIM + n0 + l16;
#pragma unroll
        for (int j = 0; j < 2; j++)
          atomicAdd(&dst[j*16], acc[i][j][r]);
      }
    }
  }
}

extern "C" void kernel_launch(void* const* d_in, const int* in_sizes, int n_in,
                              void* d_out, int out_size, void* d_ws, size_t ws_size,
                              hipStream_t stream)
{
  const float* x    = (const float*)d_in[0];
  const float* tw   = (const float*)d_in[1];
  const int*   tids = (const int*)d_in[2];
  const int*   w13  = (const int*)d_in[3];
  const int*   w13s = (const int*)d_in[4];
  const int*   w2   = (const int*)d_in[5];
  const int*   w2s  = (const int*)d_in[6];
  float* out = (float*)d_out;

  char* ws = (char*)d_ws;
  size_t off = 0;
  auto alloc = [&](size_t bytes) { void* p = ws + off; off = (off + bytes + 255) & ~(size_t)255; return p; };
  float* combs   = (float*)alloc((size_t)NEXP*T_TOK*4);
  short* lists   = (short*)alloc((size_t)NEXP*T_TOK*2);
  int*   counts  = (int*)alloc(64*4);
  int*   offsets = (int*)alloc(64*4);
  ushort* a_buf  = (ushort*)alloc((size_t)T_TOK*TOPK*IDIM*2);   // 6.29 MB
  ushort* xq     = (ushort*)(ws + off);                         // 2.1 MB

  qdq_route_kernel<<<(T_TOK*DDIM)/2048 + 1, 512, 0, stream>>>(
      x, xq, tids, tw, counts, offsets, lists, combs);
  gemm1_kernel<<<dim3(NEXP, IDIM/16, 2), 256, 0, stream>>>(
      xq, w13, w13s, counts, offsets, lists, combs, a_buf);
  gemm2_kernel<<<dim3(NEXP, DDIM/32, 2), 256, 0, stream>>>(
      a_buf, w2, w2s, counts, offsets, lists, out);
}

// Round 11
// 277.045 us; speedup vs baseline: 1.1967x; 1.1967x over previous
//
#include <hip/hip_runtime.h>
#include <stdint.h>
#include <math.h>

#define T_TOK 512
#define DDIM  2048
#define IDIM  768
#define NEXP  16
#define TOPK  8
#define LDB   72    // LDS B row stride (bf16 units)

typedef __attribute__((ext_vector_type(8))) short bf16x8;
typedef __attribute__((ext_vector_type(4))) float f32x4;

// Barrier that does NOT drain outstanding global loads (vmcnt): only LDS ops.
__device__ __forceinline__ void lds_barrier() {
  asm volatile("s_waitcnt lgkmcnt(0)" ::: "memory");
  __builtin_amdgcn_s_barrier();
}

// ---------- fp8 e4m3fn RTNE quant-dequant (fp32-exact, result fits bf16) ----------
__device__ __forceinline__ float e4m3_rtne(float f) {
  uint32_t u = __float_as_uint(f);
  uint32_t sign = u & 0x80000000u;
  uint32_t a = u & 0x7FFFFFFFu;
  float fa = __uint_as_float(a);
  float out;
  if (fa >= 0.015625f) {            // normal: keep 3 mantissa bits, RTNE
    uint32_t lsb = (a >> 20) & 1u;
    a += 0x0007FFFFu + lsb;
    a &= 0xFFF00000u;
    out = __uint_as_float(a);
  } else {                          // subnormal: quantum 2^-9
    out = rintf(fa * 512.0f) * 0.001953125f;
  }
  return __uint_as_float(__float_as_uint(out) | sign);
}

// ---------- fused qdq (blocks 0..N-2) + routing (last block) ----------
__global__ __launch_bounds__(512) void qdq_route_kernel(
    const float* __restrict__ x, ushort* __restrict__ xq,
    const int* __restrict__ ids, const float* __restrict__ wts,
    int* __restrict__ counts, int* __restrict__ offsets,
    short* __restrict__ lists, float* __restrict__ combs)
{
  if ((int)blockIdx.x < (int)gridDim.x - 1) {
    int idx4 = blockIdx.x * 512 + threadIdx.x;
    float4 v = ((const float4*)x)[idx4];
    float a = fmaxf(fmaxf(fabsf(v.x), fabsf(v.y)), fmaxf(fabsf(v.z), fabsf(v.w)));
#pragma unroll
    for (int m = 4; m >= 1; m >>= 1)
      a = fmaxf(a, __shfl_xor(a, m, 8));
    a = fmaxf(a, 1e-4f);
    float scale = a / 448.0f;
    uint32_t b = __float_as_uint(scale);
    uint32_t ex = ((b >> 23) & 255u) + ((b & 0x7FFFFFu) ? 1u : 0u);
    ex = ex < 1u ? 1u : (ex > 254u ? 254u : ex);
    float rscale = __uint_as_float(ex << 23);
    float inv = 1.0f / rscale;
    uint32_t r0 = __float_as_uint(e4m3_rtne(v.x * inv) * rscale) >> 16;
    uint32_t r1 = __float_as_uint(e4m3_rtne(v.y * inv) * rscale) >> 16;
    uint32_t r2 = __float_as_uint(e4m3_rtne(v.z * inv) * rscale) >> 16;
    uint32_t r3 = __float_as_uint(e4m3_rtne(v.w * inv) * rscale) >> 16;
    ((uint2*)xq)[idx4] = make_uint2(r0 | (r1 << 16), r2 | (r3 << 16));
  } else {
    __shared__ int scnt[NEXP];
    int t = threadIdx.x;
    if (t < NEXP) scnt[t] = 0;
    __syncthreads();
    int  myid[TOPK];
    float myw[TOPK];
#pragma unroll
    for (int k = 0; k < TOPK; k++) { myid[k] = ids[t*TOPK+k]; myw[k] = wts[t*TOPK+k]; }
    for (int e = 0; e < NEXP; e++) {
      float s = 0.f; bool r = false;
#pragma unroll
      for (int k = 0; k < TOPK; k++) if (myid[k] == e) { s += myw[k]; r = true; }
      if (r) {
        int slot = atomicAdd(&scnt[e], 1);
        lists[(e<<9) + slot] = (short)t;
        combs[(e<<9) + slot] = s;
      }
    }
    __syncthreads();
    if (t == 0) {
      int acc = 0;
      for (int e = 0; e < NEXP; e++) {
        offsets[e] = acc;
        int c = scnt[e];
        counts[e] = c;
        acc += c;
      }
      offsets[NEXP] = acc;
    }
  }
}

// ---------- fp4 -> bf16 via v_perm LUT; S = (sf-1)<<1 ----------
__device__ __forceinline__ void deq8(int4 w0, int4 w1, uint32_t S, ushort* dst) {
  uint32_t base = S << 6;
  uint32_t E01 = base << 16;                                   // e0=0 | e1=base
  uint32_t E23 = ((base + 192u) << 16) | (base + 128u);        // e2 | e3
  uint32_t E45 = ((base + 320u) << 16) | (base + 256u);        // e4 | e5
  uint32_t E67 = ((base + 448u) << 16) | (base + 384u);        // e6 | e7
  uint32_t lutLoA = __builtin_amdgcn_perm(E23, E01, 0x06040200u);
  uint32_t lutHiA = __builtin_amdgcn_perm(E23, E01, 0x07050301u);
  uint32_t lutLoB = __builtin_amdgcn_perm(E67, E45, 0x06040200u);
  uint32_t lutHiB = __builtin_amdgcn_perm(E67, E45, 0x07050301u);
  int wi[8] = {w0.x,w0.y,w0.z,w0.w, w1.x,w1.y,w1.z,w1.w};
  uint32_t od[8];
#pragma unroll
  for (int c = 0; c < 8; c += 2) {
    uint32_t a = (uint32_t)wi[c], b = (uint32_t)wi[c+1];
    uint32_t selm = ((a | (a << 4)) & 0x0707u) | ((((b | (b << 4)) & 0x0707u)) << 16);
    uint32_t sgn  = (((a << 4) | (a << 8)) & 0x8080u) | (((((b << 4) | (b << 8)) & 0x8080u)) << 16);
    uint32_t loB = __builtin_amdgcn_perm(lutLoB, lutLoA, selm);
    uint32_t hiB = __builtin_amdgcn_perm(lutHiB, lutHiA, selm) | sgn;
    od[c]   = __builtin_amdgcn_perm(hiB, loB, 0x05010400u);
    od[c+1] = __builtin_amdgcn_perm(hiB, loB, 0x07030602u);
  }
  *(uint4*)dst       = make_uint4(od[0], od[1], od[2], od[3]);
  *(uint4*)(dst + 8) = make_uint4(od[4], od[5], od[6], od[7]);
}

// ---------- GEMM1: M=128 (4 waves x 32 rows), N=32 i-cols (gate+up), BK=64 ----------
// 4-buffer LDS rotation, ONE barrier per 2 sub-iters: pair k reads bufs
// {t&3,(t+1)&3}, dequant-writes w(t+2),w(t+3) into the other two (disjoint).
__global__ __launch_bounds__(256,3) void gemm1_kernel(
    const ushort* __restrict__ xq, const int* __restrict__ w13,
    const int* __restrict__ w13s, const int* __restrict__ counts,
    const int* __restrict__ offsets, const short* __restrict__ lists,
    const float* __restrict__ combs, ushort* __restrict__ a_buf)
{
  const int e  = blockIdx.x;
  const int i0 = blockIdx.y << 5;
  const int m0 = blockIdx.z << 7;
  const int cnt = counts[e];
  if (m0 >= cnt) return;
  const int NIT = DDIM / 64;   // 32, even

  __shared__ __align__(16) ushort Bsh[4][64*LDB];
  __shared__ int   toks[128];
  __shared__ float cmbs[128];

  const int tid = threadIdx.x;
  if (tid < 128) {
    int m = m0 + tid; bool v = m < cnt;
    toks[tid] = v ? (int)lists[(e<<9)+m] : 0;
    cmbs[tid] = v ? combs[(e<<9)+m] : 0.f;
  }
  __syncthreads();

  const int wv = tid >> 6, l = tid & 63, l16 = l & 15, q = l >> 4;

  const ushort* arow[2];
#pragma unroll
  for (int i = 0; i < 2; i++)
    arow[i] = xq + (size_t)toks[wv*32 + i*16 + l16]*DDIM + q*8;

  const int rb = tid >> 2, hq = tid & 3;
  const int feat = (rb < 32) ? (i0 + rb) : (IDIM + i0 + (rb - 32));
  const int* wrow = w13 + ((size_t)e*(2*IDIM) + feat)*(DDIM/2) + hq*8;
  const int* srow = w13s + ((size_t)e*(2*IDIM) + feat)*(DDIM/32) + (hq >> 1);
  const int bdst = rb*LDB + hq*16;

  f32x4 acc[2][4];
#pragma unroll
  for (int i = 0; i < 2; i++)
#pragma unroll
    for (int j = 0; j < 4; j++) acc[i][j] = (f32x4){0.f,0.f,0.f,0.f};

  bf16x8 aA[2][2], aB[2][2];
  int4 wc00, wc01, wc10, wc11;   // current pair staging: w(t+2), w(t+3)
  uint32_t Sc0, Sc1;

  // ---- prologue: deq w(0)->buf0, w(1)->buf1; stage w(2),w(3); load a(0),a(1) ----
  {
    int4 t0 = *(const int4*)(wrow);
    int4 t1 = *(const int4*)(wrow + 4);
    deq8(t0, t1, (((uint32_t)srow[0]) - 1u) << 1, &Bsh[0][bdst]);
    t0 = *(const int4*)(wrow + 32);
    t1 = *(const int4*)(wrow + 36);
    deq8(t0, t1, (((uint32_t)srow[2]) - 1u) << 1, &Bsh[1][bdst]);
  }
  wc00 = *(const int4*)(wrow + 64);  wc01 = *(const int4*)(wrow + 68);
  Sc0  = (((uint32_t)srow[4]) - 1u) << 1;
  wc10 = *(const int4*)(wrow + 96);  wc11 = *(const int4*)(wrow + 100);
  Sc1  = (((uint32_t)srow[6]) - 1u) << 1;
#pragma unroll
  for (int i = 0; i < 2; i++)
#pragma unroll
    for (int s = 0; s < 2; s++) {
      aA[i][s] = *(const bf16x8*)(arow[i] + s*32);          // a(0)
      aB[i][s] = *(const bf16x8*)(arow[i] + 64 + s*32);     // a(1)
    }
  lds_barrier();

  for (int t = 0; t < NIT; t += 2) {
    const int idx = (t >> 1) & 1;
    ushort* R0 = Bsh[2*idx];
    ushort* R1 = Bsh[2*idx + 1];
    ushort* W0 = Bsh[2 - 2*idx];
    ushort* W1 = Bsh[3 - 2*idx];
    int t4 = t + 4 < NIT ? t + 4 : NIT - 1;
    int t5 = t + 5 < NIT ? t + 5 : NIT - 1;
    int4 wn00 = *(const int4*)(wrow + t4*32);
    int4 wn01 = *(const int4*)(wrow + t4*32 + 4);
    uint32_t Sn0 = (((uint32_t)srow[t4*2]) - 1u) << 1;
    int4 wn10 = *(const int4*)(wrow + t5*32);
    int4 wn11 = *(const int4*)(wrow + t5*32 + 4);
    uint32_t Sn1 = (((uint32_t)srow[t5*2]) - 1u) << 1;

    // ---- phase A: MFMA(R0, aA); deq w(t+2)->W0; load a(t+2)->aA
#pragma unroll
    for (int s = 0; s < 2; s++) {
      bf16x8 bfr[4];
#pragma unroll
      for (int j = 0; j < 4; j++)
        bfr[j] = *(const bf16x8*)&R0[(j*16 + l16)*LDB + s*32 + q*8];
#pragma unroll
      for (int i = 0; i < 2; i++)
#pragma unroll
        for (int j = 0; j < 4; j++)
          acc[i][j] = __builtin_amdgcn_mfma_f32_16x16x32_bf16(aA[i][s], bfr[j], acc[i][j], 0, 0, 0);
    }
    deq8(wc00, wc01, Sc0, &W0[bdst]);
    {
      int t2 = t + 2 < NIT ? t + 2 : NIT - 1;
#pragma unroll
      for (int i = 0; i < 2; i++)
#pragma unroll
        for (int s = 0; s < 2; s++)
          aA[i][s] = *(const bf16x8*)(arow[i] + t2*64 + s*32);
    }

    // ---- phase B: MFMA(R1, aB); deq w(t+3)->W1; load a(t+3)->aB  (no barrier between)
#pragma unroll
    for (int s = 0; s < 2; s++) {
      bf16x8 bfr[4];
#pragma unroll
      for (int j = 0; j < 4; j++)
        bfr[j] = *(const bf16x8*)&R1[(j*16 + l16)*LDB + s*32 + q*8];
#pragma unroll
      for (int i = 0; i < 2; i++)
#pragma unroll
        for (int j = 0; j < 4; j++)
          acc[i][j] = __builtin_amdgcn_mfma_f32_16x16x32_bf16(aB[i][s], bfr[j], acc[i][j], 0, 0, 0);
    }
    deq8(wc10, wc11, Sc1, &W1[bdst]);
    {
      int t3 = t + 3 < NIT ? t + 3 : NIT - 1;
#pragma unroll
      for (int i = 0; i < 2; i++)
#pragma unroll
        for (int s = 0; s < 2; s++)
          aB[i][s] = *(const bf16x8*)(arow[i] + t3*64 + s*32);
    }
    wc00 = wn00; wc01 = wn01; Sc0 = Sn0;
    wc10 = wn10; wc11 = wn11; Sc1 = Sn1;
    lds_barrier();
  }

  const int obase = offsets[e];
#pragma unroll
  for (int i = 0; i < 2; i++) {
#pragma unroll
    for (int r = 0; r < 4; r++) {
      int mrow = wv*32 + i*16 + q*4 + r;   // C/D: row=(lane>>4)*4+reg, col=lane&15
      int gm = m0 + mrow;
      if (gm < cnt) {
        float c = cmbs[mrow];
        ushort* dst = a_buf + (size_t)(obase + gm)*IDIM + i0 + l16;
#pragma unroll
        for (int jj = 0; jj < 2; jj++) {
          float g = acc[i][jj][r], u = acc[i][jj+2][r];
          float val = (g / (1.f + expf(-g))) * u * c;   // comb folded (linear downstream)
          uint32_t bb = __float_as_uint(val);
          bb += 0x7FFFu + ((bb >> 16) & 1u);            // RTNE to bf16
          dst[jj*16] = (ushort)(bb >> 16);
        }
      }
    }
  }
}

// ---------- GEMM2: M=128 (4 waves x 32), N=64 d-cols, BK=64, 4-buffer, fused combine ----------
__global__ __launch_bounds__(256,4) void gemm2_kernel(
    const ushort* __restrict__ a_buf, const int* __restrict__ w2,
    const int* __restrict__ w2s, const int* __restrict__ counts,
    const int* __restrict__ offsets, const short* __restrict__ lists,
    float* __restrict__ out)
{
  const int e  = blockIdx.x;
  const int n0 = blockIdx.y << 6;
  const int m0 = blockIdx.z << 7;
  const int cnt = counts[e];
  if (m0 >= cnt) return;
  const int NIT = IDIM / 64;   // 12, even

  __shared__ __align__(16) ushort Bsh[4][64*LDB];

  const int tid = threadIdx.x;
  const int wv = tid >> 6, l = tid & 63, l16 = l & 15, q = l >> 4;
  const int obase = offsets[e];

  const ushort* arow[2];
#pragma unroll
  for (int i = 0; i < 2; i++) {
    int gm = m0 + wv*32 + i*16 + l16;
    int rowc = (gm < cnt) ? gm : 0;
    arow[i] = a_buf + (size_t)(obase + rowc)*IDIM + q*8;
  }

  const int rb = tid >> 2, hq = tid & 3;
  const int* wrow = w2 + ((size_t)e*DDIM + n0 + rb)*(IDIM/2) + hq*8;
  const int* srow = w2s + ((size_t)e*DDIM + n0 + rb)*(IDIM/32) + (hq >> 1);
  const int bdst = rb*LDB + hq*16;

  f32x4 acc[2][4];
#pragma unroll
  for (int i = 0; i < 2; i++)
#pragma unroll
    for (int j = 0; j < 4; j++) acc[i][j] = (f32x4){0.f,0.f,0.f,0.f};

  bf16x8 aA[2][2], aB[2][2];
  int4 wc00, wc01, wc10, wc11;
  uint32_t Sc0, Sc1;

  {
    int4 t0 = *(const int4*)(wrow);
    int4 t1 = *(const int4*)(wrow + 4);
    deq8(t0, t1, (((uint32_t)srow[0]) - 1u) << 1, &Bsh[0][bdst]);
    t0 = *(const int4*)(wrow + 32);
    t1 = *(const int4*)(wrow + 36);
    deq8(t0, t1, (((uint32_t)srow[2]) - 1u) << 1, &Bsh[1][bdst]);
  }
  wc00 = *(const int4*)(wrow + 64);  wc01 = *(const int4*)(wrow + 68);
  Sc0  = (((uint32_t)srow[4]) - 1u) << 1;
  wc10 = *(const int4*)(wrow + 96);  wc11 = *(const int4*)(wrow + 100);
  Sc1  = (((uint32_t)srow[6]) - 1u) << 1;
#pragma unroll
  for (int i = 0; i < 2; i++)
#pragma unroll
    for (int s = 0; s < 2; s++) {
      aA[i][s] = *(const bf16x8*)(arow[i] + s*32);
      aB[i][s] = *(const bf16x8*)(arow[i] + 64 + s*32);
    }
  lds_barrier();

  for (int t = 0; t < NIT; t += 2) {
    const int idx = (t >> 1) & 1;
    ushort* R0 = Bsh[2*idx];
    ushort* R1 = Bsh[2*idx + 1];
    ushort* W0 = Bsh[2 - 2*idx];
    ushort* W1 = Bsh[3 - 2*idx];
    int t4 = t + 4 < NIT ? t + 4 : NIT - 1;
    int t5 = t + 5 < NIT ? t + 5 : NIT - 1;
    int4 wn00 = *(const int4*)(wrow + t4*32);
    int4 wn01 = *(const int4*)(wrow + t4*32 + 4);
    uint32_t Sn0 = (((uint32_t)srow[t4*2]) - 1u) << 1;
    int4 wn10 = *(const int4*)(wrow + t5*32);
    int4 wn11 = *(const int4*)(wrow + t5*32 + 4);
    uint32_t Sn1 = (((uint32_t)srow[t5*2]) - 1u) << 1;

#pragma unroll
    for (int s = 0; s < 2; s++) {
      bf16x8 bfr[4];
#pragma unroll
      for (int j = 0; j < 4; j++)
        bfr[j] = *(const bf16x8*)&R0[(j*16 + l16)*LDB + s*32 + q*8];
#pragma unroll
      for (int i = 0; i < 2; i++)
#pragma unroll
        for (int j = 0; j < 4; j++)
          acc[i][j] = __builtin_amdgcn_mfma_f32_16x16x32_bf16(aA[i][s], bfr[j], acc[i][j], 0, 0, 0);
    }
    deq8(wc00, wc01, Sc0, &W0[bdst]);
    {
      int t2 = t + 2 < NIT ? t + 2 : NIT - 1;
#pragma unroll
      for (int i = 0; i < 2; i++)
#pragma unroll
        for (int s = 0; s < 2; s++)
          aA[i][s] = *(const bf16x8*)(arow[i] + t2*64 + s*32);
    }

#pragma unroll
    for (int s = 0; s < 2; s++) {
      bf16x8 bfr[4];
#pragma unroll
      for (int j = 0; j < 4; j++)
        bfr[j] = *(const bf16x8*)&R1[(j*16 + l16)*LDB + s*32 + q*8];
#pragma unroll
      for (int i = 0; i < 2; i++)
#pragma unroll
        for (int j = 0; j < 4; j++)
          acc[i][j] = __builtin_amdgcn_mfma_f32_16x16x32_bf16(aB[i][s], bfr[j], acc[i][j], 0, 0, 0);
    }
    deq8(wc10, wc11, Sc1, &W1[bdst]);
    {
      int t3 = t + 3 < NIT ? t + 3 : NIT - 1;
#pragma unroll
      for (int i = 0; i < 2; i++)
#pragma unroll
        for (int s = 0; s < 2; s++)
          aB[i][s] = *(const bf16x8*)(arow[i] + t3*64 + s*32);
    }
    wc00 = wn00; wc01 = wn01; Sc0 = Sn0;
    wc10 = wn10; wc11 = wn11; Sc1 = Sn1;
    lds_barrier();
  }

#pragma unroll
  for (int i = 0; i < 2; i++) {
#pragma unroll
    for (int r = 0; r < 4; r++) {
      int mrow = wv*32 + i*16 + q*4 + r;
      int gm = m0 + mrow;
      if (gm < cnt) {
        int tok = (int)lists[(e<<9) + gm];
        float* dst = out + (size_t)tok*DDIM + n0 + l16;
#pragma unroll
        for (int j = 0; j < 4; j++)
          atomicAdd(&dst[j*16], acc[i][j][r]);
      }
    }
  }
}

extern "C" void kernel_launch(void* const* d_in, const int* in_sizes, int n_in,
                              void* d_out, int out_size, void* d_ws, size_t ws_size,
                              hipStream_t stream)
{
  const float* x    = (const float*)d_in[0];
  const float* tw   = (const float*)d_in[1];
  const int*   tids = (const int*)d_in[2];
  const int*   w13  = (const int*)d_in[3];
  const int*   w13s = (const int*)d_in[4];
  const int*   w2   = (const int*)d_in[5];
  const int*   w2s  = (const int*)d_in[6];
  float* out = (float*)d_out;

  char* ws = (char*)d_ws;
  size_t off = 0;
  auto alloc = [&](size_t bytes) { void* p = ws + off; off = (off + bytes + 255) & ~(size_t)255; return p; };
  float* combs   = (float*)alloc((size_t)NEXP*T_TOK*4);
  short* lists   = (short*)alloc((size_t)NEXP*T_TOK*2);
  int*   counts  = (int*)alloc(64*4);
  int*   offsets = (int*)alloc(64*4);
  ushort* a_buf  = (ushort*)alloc((size_t)T_TOK*TOPK*IDIM*2);   // 6.29 MB
  ushort* xq     = (ushort*)(ws + off);                         // 2.1 MB

  qdq_route_kernel<<<(T_TOK*DDIM)/2048 + 1, 512, 0, stream>>>(
      x, xq, tids, tw, counts, offsets, lists, combs);
  gemm1_kernel<<<dim3(NEXP, IDIM/32, 4), 256, 0, stream>>>(
      xq, w13, w13s, counts, offsets, lists, combs, a_buf);
  gemm2_kernel<<<dim3(NEXP, DDIM/64, 4), 256, 0, stream>>>(
      a_buf, w2, w2s, counts, offsets, lists, out);
}